// Round 1
// baseline (260.733 us; speedup 1.0000x reference)
//
#include <hip/hip_runtime.h>
#include <hip/hip_bf16.h>
#include <math.h>

// Problem constants
#define Bdim 2
#define Tdim 512
#define Cdim 256
#define Hdim 8
#define Edim 32
#define NTYPES 16

// ---------------------------------------------------------------------------
// Kernel 1: edge tables  ekt[t][c] = sum_k emb[t][k] * w_edge_k[k][c]
//           evt[t][c] = sum_k emb[t][k] * w_edge_v[k][c]
// grid = 16 (one block per edge type), block = 256 (one thread per c)
// ---------------------------------------------------------------------------
__global__ __launch_bounds__(256) void edge_tables_kernel(
    const float* __restrict__ emb, const float* __restrict__ wk,
    const float* __restrict__ wv, float* __restrict__ ekt,
    float* __restrict__ evt)
{
    int t = blockIdx.x;
    int c = threadIdx.x;
    __shared__ float se[Cdim];
    se[c] = emb[t * Cdim + c];
    __syncthreads();
    float a = 0.f, b = 0.f;
    for (int k = 0; k < Cdim; ++k) {
        float ev = se[k];
        a = fmaf(ev, wk[k * Cdim + c], a);
        b = fmaf(ev, wv[k * Cdim + c], b);
    }
    ekt[t * Cdim + c] = a;
    evt[t * Cdim + c] = b;
}

// ---------------------------------------------------------------------------
// Kernel 2: qkv GEMM  (M=1024, K=256, N=768), A=x row-major, Bw=w_attn
// 64x64 tile, 256 threads, 4x4 per thread. Epilogue scatters to
// qT/kT/vT in (B,H,T,E) layout.
// ---------------------------------------------------------------------------
__global__ __launch_bounds__(256) void qkv_gemm_kernel(
    const float* __restrict__ A, const float* __restrict__ Bw,
    float* __restrict__ qT, float* __restrict__ kT, float* __restrict__ vT)
{
    const int M = Bdim * Tdim;       // 1024
    const int N = 3 * Cdim;          // 768
    const int K = Cdim;              // 256
    (void)M;
    __shared__ float As[16][65];
    __shared__ float Bs[16][64];
    int m0 = blockIdx.y * 64;
    int n0 = blockIdx.x * 64;
    int tid = threadIdx.x;
    int tr = tid >> 4, tc = tid & 15;
    float acc[4][4] = {};
    int ar = tid >> 2, akq = (tid & 3) * 4;      // A tile load: row, k-quad
    int bkr = tid >> 4, bcq = (tid & 15) * 4;    // B tile load: k-row, col-quad

    for (int k0 = 0; k0 < K; k0 += 16) {
        float4 av = *(const float4*)(A + (size_t)(m0 + ar) * K + k0 + akq);
        float4 bv = *(const float4*)(Bw + (size_t)(k0 + bkr) * N + n0 + bcq);
        As[akq + 0][ar] = av.x;
        As[akq + 1][ar] = av.y;
        As[akq + 2][ar] = av.z;
        As[akq + 3][ar] = av.w;
        *(float4*)&Bs[bkr][bcq] = bv;
        __syncthreads();
#pragma unroll
        for (int kk = 0; kk < 16; ++kk) {
            float a0 = As[kk][tr * 4 + 0];
            float a1 = As[kk][tr * 4 + 1];
            float a2 = As[kk][tr * 4 + 2];
            float a3 = As[kk][tr * 4 + 3];
            float b0 = Bs[kk][tc * 4 + 0];
            float b1 = Bs[kk][tc * 4 + 1];
            float b2 = Bs[kk][tc * 4 + 2];
            float b3 = Bs[kk][tc * 4 + 3];
            acc[0][0] = fmaf(a0, b0, acc[0][0]);
            acc[0][1] = fmaf(a0, b1, acc[0][1]);
            acc[0][2] = fmaf(a0, b2, acc[0][2]);
            acc[0][3] = fmaf(a0, b3, acc[0][3]);
            acc[1][0] = fmaf(a1, b0, acc[1][0]);
            acc[1][1] = fmaf(a1, b1, acc[1][1]);
            acc[1][2] = fmaf(a1, b2, acc[1][2]);
            acc[1][3] = fmaf(a1, b3, acc[1][3]);
            acc[2][0] = fmaf(a2, b0, acc[2][0]);
            acc[2][1] = fmaf(a2, b1, acc[2][1]);
            acc[2][2] = fmaf(a2, b2, acc[2][2]);
            acc[2][3] = fmaf(a2, b3, acc[2][3]);
            acc[3][0] = fmaf(a3, b0, acc[3][0]);
            acc[3][1] = fmaf(a3, b1, acc[3][1]);
            acc[3][2] = fmaf(a3, b2, acc[3][2]);
            acc[3][3] = fmaf(a3, b3, acc[3][3]);
        }
        __syncthreads();
    }
#pragma unroll
    for (int i = 0; i < 4; ++i) {
#pragma unroll
        for (int j = 0; j < 4; ++j) {
            int m = m0 + tr * 4 + i;
            int n = n0 + tc * 4 + j;
            int b = m >> 9;             // /T
            int t = m & (Tdim - 1);
            int sec = n >> 8;           // 0=q,1=k,2=v
            int cc = n & (Cdim - 1);
            int h = cc >> 5;
            int e = cc & (Edim - 1);
            float* dst = (sec == 0) ? qT : (sec == 1) ? kT : vT;
            dst[(((size_t)b * Hdim + h) * Tdim + t) * Edim + e] = acc[i][j];
        }
    }
}

// ---------------------------------------------------------------------------
// Kernel 3: attention. One block per (b,h,i). 256 threads = 8 groups x 32.
// scores[j] = (1/sqrt(E)) * sum_e q[i,e]*k[j,e]*ekt[bm[b,j,i],h,e]
//             + abt[bm[b,i,j],h]        for j<=i
// softmax over j, then y[i,e] = sum_j p[j]*v[j,e]*evt[bm[b,j,i],h,e]
// y written in (B,T,C) layout for the proj GEMM.
// ---------------------------------------------------------------------------
__global__ __launch_bounds__(256) void attn_kernel(
    const float* __restrict__ qT, const float* __restrict__ kT,
    const float* __restrict__ vT, const int* __restrict__ bm,
    const float* __restrict__ ekt, const float* __restrict__ evt,
    const float* __restrict__ abt, float* __restrict__ y)
{
    int blk = blockIdx.x;            // (b*H + h)*T + i
    int i = blk & (Tdim - 1);
    int bh = blk >> 9;
    int h = bh & (Hdim - 1);
    int b = bh >> 3;

    __shared__ float sq[Edim];
    __shared__ float sekt[NTYPES][Edim];
    __shared__ float sevt[NTYPES][Edim];
    __shared__ float ss[Tdim];
    __shared__ int st1[Tdim];
    __shared__ float sred[16];
    __shared__ float spart[8][Edim];

    int tid = threadIdx.x;
    if (tid < Edim) sq[tid] = qT[((size_t)bh * Tdim + i) * Edim + tid];
    for (int idx = tid; idx < NTYPES * Edim; idx += 256) {
        int ty = idx >> 5, ee = idx & 31;
        sekt[ty][ee] = ekt[ty * Cdim + h * Edim + ee];
        sevt[ty][ee] = evt[ty * Cdim + h * Edim + ee];
    }
    __syncthreads();

    int e = tid & 31;
    int g = tid >> 5;                // 8 groups of 32 lanes
    const float* kbase = kT + (size_t)bh * Tdim * Edim;
    const float* vbase = vT + (size_t)bh * Tdim * Edim;
    const int* bmb = bm + (size_t)b * Tdim * Tdim;
    const float inv_scale = 0.17677669529663687f;  // 1/sqrt(32)

    // Phase 1: scores
    for (int j = g; j <= i; j += 8) {
        int t1 = bmb[j * Tdim + i];
        float p = sq[e] * kbase[j * Edim + e] * sekt[t1][e];
        p += __shfl_down(p, 16, 32);
        p += __shfl_down(p, 8, 32);
        p += __shfl_down(p, 4, 32);
        p += __shfl_down(p, 2, 32);
        p += __shfl_down(p, 1, 32);
        if (e == 0) {
            int t2 = bmb[i * Tdim + j];
            ss[j] = p * inv_scale + abt[t2 * Hdim + h];
            st1[j] = t1;
        }
    }
    __syncthreads();

    // Phase 2: softmax over ss[0..i]
    int n = i + 1;
    float mx = -INFINITY;
    for (int j = tid; j < n; j += 256) mx = fmaxf(mx, ss[j]);
    for (int off = 32; off; off >>= 1) mx = fmaxf(mx, __shfl_down(mx, off));
    if ((tid & 63) == 0) sred[tid >> 6] = mx;
    __syncthreads();
    mx = fmaxf(fmaxf(sred[0], sred[1]), fmaxf(sred[2], sred[3]));
    float sm = 0.f;
    for (int j = tid; j < n; j += 256) {
        float pe = __expf(ss[j] - mx);
        ss[j] = pe;
        sm += pe;
    }
    for (int off = 32; off; off >>= 1) sm += __shfl_down(sm, off);
    if ((tid & 63) == 0) sred[4 + (tid >> 6)] = sm;
    __syncthreads();
    float inv_sum = 1.0f / (sred[4] + sred[5] + sred[6] + sred[7]);

    // Phase 3: modulated PV
    float acc = 0.f;
    for (int j = g; j <= i; j += 8) {
        acc = fmaf(ss[j] * sevt[st1[j]][e], vbase[j * Edim + e], acc);
    }
    spart[g][e] = acc;
    __syncthreads();
    if (tid < Edim) {
        float yv = 0.f;
#pragma unroll
        for (int gg = 0; gg < 8; ++gg) yv += spart[gg][tid];
        y[((size_t)(b * Tdim + i)) * Cdim + h * Edim + tid] = yv * inv_sum;
    }
}

// ---------------------------------------------------------------------------
// Kernel 4: proj GEMM (M=1024, K=256, N=256) -> d_out (B,T,C)
// ---------------------------------------------------------------------------
__global__ __launch_bounds__(256) void proj_gemm_kernel(
    const float* __restrict__ A, const float* __restrict__ Bw,
    float* __restrict__ out)
{
    const int N = Cdim;
    const int K = Cdim;
    __shared__ float As[16][65];
    __shared__ float Bs[16][64];
    int m0 = blockIdx.y * 64;
    int n0 = blockIdx.x * 64;
    int tid = threadIdx.x;
    int tr = tid >> 4, tc = tid & 15;
    float acc[4][4] = {};
    int ar = tid >> 2, akq = (tid & 3) * 4;
    int bkr = tid >> 4, bcq = (tid & 15) * 4;

    for (int k0 = 0; k0 < K; k0 += 16) {
        float4 av = *(const float4*)(A + (size_t)(m0 + ar) * K + k0 + akq);
        float4 bv = *(const float4*)(Bw + (size_t)(k0 + bkr) * N + n0 + bcq);
        As[akq + 0][ar] = av.x;
        As[akq + 1][ar] = av.y;
        As[akq + 2][ar] = av.z;
        As[akq + 3][ar] = av.w;
        *(float4*)&Bs[bkr][bcq] = bv;
        __syncthreads();
#pragma unroll
        for (int kk = 0; kk < 16; ++kk) {
            float a0 = As[kk][tr * 4 + 0];
            float a1 = As[kk][tr * 4 + 1];
            float a2 = As[kk][tr * 4 + 2];
            float a3 = As[kk][tr * 4 + 3];
            float b0 = Bs[kk][tc * 4 + 0];
            float b1 = Bs[kk][tc * 4 + 1];
            float b2 = Bs[kk][tc * 4 + 2];
            float b3 = Bs[kk][tc * 4 + 3];
            acc[0][0] = fmaf(a0, b0, acc[0][0]);
            acc[0][1] = fmaf(a0, b1, acc[0][1]);
            acc[0][2] = fmaf(a0, b2, acc[0][2]);
            acc[0][3] = fmaf(a0, b3, acc[0][3]);
            acc[1][0] = fmaf(a1, b0, acc[1][0]);
            acc[1][1] = fmaf(a1, b1, acc[1][1]);
            acc[1][2] = fmaf(a1, b2, acc[1][2]);
            acc[1][3] = fmaf(a1, b3, acc[1][3]);
            acc[2][0] = fmaf(a2, b0, acc[2][0]);
            acc[2][1] = fmaf(a2, b1, acc[2][1]);
            acc[2][2] = fmaf(a2, b2, acc[2][2]);
            acc[2][3] = fmaf(a2, b3, acc[2][3]);
            acc[3][0] = fmaf(a3, b0, acc[3][0]);
            acc[3][1] = fmaf(a3, b1, acc[3][1]);
            acc[3][2] = fmaf(a3, b2, acc[3][2]);
            acc[3][3] = fmaf(a3, b3, acc[3][3]);
        }
        __syncthreads();
    }
#pragma unroll
    for (int i = 0; i < 4; ++i) {
#pragma unroll
        for (int j = 0; j < 4; ++j) {
            int m = m0 + tr * 4 + i;
            int nn = n0 + tc * 4 + j;
            out[(size_t)m * N + nn] = acc[i][j];
        }
    }
}

// ---------------------------------------------------------------------------
extern "C" void kernel_launch(void* const* d_in, const int* in_sizes, int n_in,
                              void* d_out, int out_size, void* d_ws, size_t ws_size,
                              hipStream_t stream) {
    (void)in_sizes; (void)n_in; (void)out_size; (void)ws_size;
    const float* x = (const float*)d_in[0];
    const int* bias_matrix = (const int*)d_in[1];
    const float* w_attn = (const float*)d_in[2];
    const float* w_proj = (const float*)d_in[3];
    const float* w_edge_k = (const float*)d_in[4];
    const float* w_edge_v = (const float*)d_in[5];
    const float* edge_emb = (const float*)d_in[6];
    const float* attn_bias = (const float*)d_in[7];
    float* out = (float*)d_out;

    // Workspace layout (floats)
    const size_t n_qkv = (size_t)Bdim * Hdim * Tdim * Edim;  // 262144 each
    float* ws = (float*)d_ws;
    float* qT = ws;
    float* kT = qT + n_qkv;
    float* vT = kT + n_qkv;
    float* y = vT + n_qkv;                                  // (B,T,C)
    float* ekt = y + (size_t)Bdim * Tdim * Cdim;
    float* evt = ekt + (size_t)NTYPES * Cdim;

    edge_tables_kernel<<<NTYPES, 256, 0, stream>>>(edge_emb, w_edge_k, w_edge_v,
                                                   ekt, evt);
    qkv_gemm_kernel<<<dim3(12, 16), 256, 0, stream>>>(x, w_attn, qT, kT, vT);
    attn_kernel<<<Bdim * Hdim * Tdim, 256, 0, stream>>>(qT, kT, vT, bias_matrix,
                                                        ekt, evt, attn_bias, y);
    proj_gemm_kernel<<<dim3(4, 16), 256, 0, stream>>>(y, w_proj, out);
}

// Round 2
// 163.835 us; speedup vs baseline: 1.5914x; 1.5914x over previous
//
#include <hip/hip_runtime.h>
#include <hip/hip_bf16.h>
#include <math.h>

// Problem constants
#define Bdim 2
#define Tdim 512
#define Cdim 256
#define Hdim 8
#define Edim 32
#define NTYPES 16
#define TI 16      // i-tile size
#define JT 128     // j-tile size

// ---------------------------------------------------------------------------
// Kernel 1: edge tables  ekt[t][c] = sum_k emb[t][k] * w_edge_k[k][c]
// ---------------------------------------------------------------------------
__global__ __launch_bounds__(256) void edge_tables_kernel(
    const float* __restrict__ emb, const float* __restrict__ wk,
    const float* __restrict__ wv, float* __restrict__ ekt,
    float* __restrict__ evt)
{
    int t = blockIdx.x;
    int c = threadIdx.x;
    __shared__ float se[Cdim];
    se[c] = emb[t * Cdim + c];
    __syncthreads();
    float a = 0.f, b = 0.f;
    for (int k = 0; k < Cdim; ++k) {
        float ev = se[k];
        a = fmaf(ev, wk[k * Cdim + c], a);
        b = fmaf(ev, wv[k * Cdim + c], b);
    }
    ekt[t * Cdim + c] = a;
    evt[t * Cdim + c] = b;
}

// ---------------------------------------------------------------------------
// Kernel 2: qkv GEMM  (M=1024, K=256, N=768) with scatter to (B,H,T,E)
// ---------------------------------------------------------------------------
__global__ __launch_bounds__(256) void qkv_gemm_kernel(
    const float* __restrict__ A, const float* __restrict__ Bw,
    float* __restrict__ qT, float* __restrict__ kT, float* __restrict__ vT)
{
    const int N = 3 * Cdim;
    const int K = Cdim;
    __shared__ float As[16][65];
    __shared__ float Bs[16][64];
    int m0 = blockIdx.y * 64;
    int n0 = blockIdx.x * 64;
    int tid = threadIdx.x;
    int tr = tid >> 4, tc = tid & 15;
    float acc[4][4] = {};
    int ar = tid >> 2, akq = (tid & 3) * 4;
    int bkr = tid >> 4, bcq = (tid & 15) * 4;

    for (int k0 = 0; k0 < K; k0 += 16) {
        float4 av = *(const float4*)(A + (size_t)(m0 + ar) * K + k0 + akq);
        float4 bv = *(const float4*)(Bw + (size_t)(k0 + bkr) * N + n0 + bcq);
        As[akq + 0][ar] = av.x;
        As[akq + 1][ar] = av.y;
        As[akq + 2][ar] = av.z;
        As[akq + 3][ar] = av.w;
        *(float4*)&Bs[bkr][bcq] = bv;
        __syncthreads();
#pragma unroll
        for (int kk = 0; kk < 16; ++kk) {
            float a0 = As[kk][tr * 4 + 0];
            float a1 = As[kk][tr * 4 + 1];
            float a2 = As[kk][tr * 4 + 2];
            float a3 = As[kk][tr * 4 + 3];
            float b0 = Bs[kk][tc * 4 + 0];
            float b1 = Bs[kk][tc * 4 + 1];
            float b2 = Bs[kk][tc * 4 + 2];
            float b3 = Bs[kk][tc * 4 + 3];
            acc[0][0] = fmaf(a0, b0, acc[0][0]);
            acc[0][1] = fmaf(a0, b1, acc[0][1]);
            acc[0][2] = fmaf(a0, b2, acc[0][2]);
            acc[0][3] = fmaf(a0, b3, acc[0][3]);
            acc[1][0] = fmaf(a1, b0, acc[1][0]);
            acc[1][1] = fmaf(a1, b1, acc[1][1]);
            acc[1][2] = fmaf(a1, b2, acc[1][2]);
            acc[1][3] = fmaf(a1, b3, acc[1][3]);
            acc[2][0] = fmaf(a2, b0, acc[2][0]);
            acc[2][1] = fmaf(a2, b1, acc[2][1]);
            acc[2][2] = fmaf(a2, b2, acc[2][2]);
            acc[2][3] = fmaf(a2, b3, acc[2][3]);
            acc[3][0] = fmaf(a3, b0, acc[3][0]);
            acc[3][1] = fmaf(a3, b1, acc[3][1]);
            acc[3][2] = fmaf(a3, b2, acc[3][2]);
            acc[3][3] = fmaf(a3, b3, acc[3][3]);
        }
        __syncthreads();
    }
#pragma unroll
    for (int i = 0; i < 4; ++i) {
#pragma unroll
        for (int j = 0; j < 4; ++j) {
            int m = m0 + tr * 4 + i;
            int n = n0 + tc * 4 + j;
            int b = m >> 9;
            int t = m & (Tdim - 1);
            int sec = n >> 8;
            int cc = n & (Cdim - 1);
            int h = cc >> 5;
            int e = cc & (Edim - 1);
            float* dst = (sec == 0) ? qT : (sec == 1) ? kT : vT;
            dst[(((size_t)b * Hdim + h) * Tdim + t) * Edim + e] = acc[i][j];
        }
    }
}

// ---------------------------------------------------------------------------
// Kernel 3: attention, restructured.
// grid = (16 tile-pairs, 16 bh), block = 512 threads (8 waves).
// Block handles i-tiles tau and 31-tau (size 16) -> perfectly balanced.
// Pass A: lane-owns-j scores with qm = q*ekt premultiplied in LDS, k in regs.
// Softmax: per-i, lane-strided + butterfly, normalization deferred (sinv).
// Pass B: 8-lane e-quad groups, v in regs, acc in 64 VGPRs, shfl_xor + LDS
// cross-wave reduction.
// ---------------------------------------------------------------------------
__global__ __launch_bounds__(512) void attn_kernel(
    const float* __restrict__ qT, const float* __restrict__ kT,
    const float* __restrict__ vT, const int* __restrict__ bm,
    const float* __restrict__ ekt, const float* __restrict__ evt,
    const float* __restrict__ abt, float* __restrict__ y)
{
    __shared__ float kv[JT][36];                 // k or v tile (quad-padded)
    __shared__ float qm[TI][NTYPES][36];         // q*ekt
    __shared__ float ss[TI][520];                // scores -> probs
    __shared__ unsigned char st1m[TI][Tdim];     // edge type bm[b,j,i]
    __shared__ float sekt[NTYPES][36];
    __shared__ float sevt[NTYPES][36];
    __shared__ float sq[TI][36];
    __shared__ float sabt[NTYPES];
    __shared__ float sinv[TI];
    __shared__ float spartW[8][TI][Edim];

    const int pairIdx = blockIdx.x;   // 0..15
    const int bh = blockIdx.y;        // 0..15
    const int h = bh & (Hdim - 1);
    const int b = bh >> 3;
    const int tid = threadIdx.x;
    const int wave = tid >> 6;
    const int lane = tid & 63;
    const float inv_scale = 0.17677669529663687f;  // 1/sqrt(32)

    const float* qbase = qT + (size_t)bh * Tdim * Edim;
    const float* kbase = kT + (size_t)bh * Tdim * Edim;
    const float* vbase = vT + (size_t)bh * Tdim * Edim;
    const int* bmb = bm + (size_t)b * Tdim * Tdim;

    // Stage per-(h) tables once
    for (int idx = tid; idx < NTYPES * 8; idx += 512) {
        int t = idx >> 3, eq = idx & 7;
        *(float4*)&sekt[t][eq * 4] = *(const float4*)&ekt[t * Cdim + h * Edim + eq * 4];
        *(float4*)&sevt[t][eq * 4] = *(const float4*)&evt[t * Cdim + h * Edim + eq * 4];
    }
    if (tid < NTYPES) sabt[tid] = abt[tid * Hdim + h];

    for (int rep = 0; rep < 2; ++rep) {
        int tau = rep ? (31 - pairIdx) : pairIdx;
        int i0 = tau * TI;
        int imax = i0 + TI - 1;
        int njt = (imax >> 7) + 1;

        __syncthreads();  // tables ready / previous rep done

        // stage q rows, build qm[ii][t][e] = q[i0+ii][e] * ekt[t][e]
        for (int idx = tid; idx < TI * 8; idx += 512) {
            int r = idx >> 3, eq = idx & 7;
            *(float4*)&sq[r][eq * 4] =
                *(const float4*)&qbase[(size_t)(i0 + r) * Edim + eq * 4];
        }
        __syncthreads();
        for (int idx = tid; idx < TI * NTYPES * 8; idx += 512) {
            int eq = idx & 7;
            int t = (idx >> 3) & (NTYPES - 1);
            int r = idx >> 7;
            float4 qv = *(float4*)&sq[r][eq * 4];
            float4 ev = *(float4*)&sekt[t][eq * 4];
            float4 o;
            o.x = qv.x * ev.x; o.y = qv.y * ev.y;
            o.z = qv.z * ev.z; o.w = qv.w * ev.w;
            *(float4*)&qm[r][t][eq * 4] = o;
        }

        // ---------------- Pass A: scores ----------------
        for (int jt = 0; jt < njt; ++jt) {
            int j0 = jt << 7;
            __syncthreads();   // previous tile consumers done (also covers qm build on jt=0)
            // stage k tile (coalesced)
            for (int idx = tid; idx < JT * 8; idx += 512) {
                int r = idx >> 3, eq = idx & 7;
                *(float4*)&kv[r][eq * 4] =
                    *(const float4*)&kbase[(size_t)(j0 + r) * Edim + eq * 4];
            }
            // stage bm[b, j, i0..i0+15] -> st1m (one int4 per thread)
            {
                int r = tid >> 2, iq = (tid & 3) * 4;
                int4 bmv = *(const int4*)&bmb[(size_t)(j0 + r) * Tdim + i0 + iq];
                st1m[iq + 0][j0 + r] = (unsigned char)bmv.x;
                st1m[iq + 1][j0 + r] = (unsigned char)bmv.y;
                st1m[iq + 2][j0 + r] = (unsigned char)bmv.z;
                st1m[iq + 3][j0 + r] = (unsigned char)bmv.w;
            }
            __syncthreads();

            int jsub = wave & 1;
            int jl = (jsub << 6) + lane;
            int j = j0 + jl;
            float4 k4[8];
#pragma unroll
            for (int eq = 0; eq < 8; ++eq) k4[eq] = *(float4*)&kv[jl][eq * 4];

#pragma unroll
            for (int u = 0; u < 4; ++u) {
                int ii = (wave >> 1) + u * 4;
                int i = i0 + ii;
                if (j0 + (jsub << 6) > i) continue;   // wave-uniform skip
                int t1 = st1m[ii][j];
                int t2 = bmb[(size_t)i * Tdim + j];   // L2-resident
                float s = 0.f;
#pragma unroll
                for (int eq = 0; eq < 8; ++eq) {
                    float4 qv = *(float4*)&qm[ii][t1][eq * 4];
                    s = fmaf(qv.x, k4[eq].x, s);
                    s = fmaf(qv.y, k4[eq].y, s);
                    s = fmaf(qv.z, k4[eq].z, s);
                    s = fmaf(qv.w, k4[eq].w, s);
                }
                if (j <= i) ss[ii][j] = s * inv_scale + sabt[t2];
            }
        }
        __syncthreads();

        // ---------------- softmax (normalization deferred) ----------------
#pragma unroll
        for (int w2 = 0; w2 < 2; ++w2) {
            int ii = wave * 2 + w2;
            int i = i0 + ii;
            float m = -1e30f;
            for (int j = lane; j <= i; j += 64) m = fmaxf(m, ss[ii][j]);
            for (int off = 32; off; off >>= 1) m = fmaxf(m, __shfl_xor(m, off));
            float sum = 0.f;
            for (int j = lane; j <= i; j += 64) {
                float p = __expf(ss[ii][j] - m);
                ss[ii][j] = p;
                sum += p;
            }
            for (int off = 32; off; off >>= 1) sum += __shfl_xor(sum, off);
            if (lane == 0) sinv[ii] = 1.0f / sum;
        }

        // ---------------- Pass B: PV ----------------
        float4 acc[TI];
#pragma unroll
        for (int ii = 0; ii < TI; ++ii) acc[ii] = make_float4(0.f, 0.f, 0.f, 0.f);
        int gid = tid >> 3;        // 64 groups of 8
        int eqg = tid & 7;         // e-quad within group
        for (int jt = 0; jt < njt; ++jt) {
            int j0 = jt << 7;
            __syncthreads();   // also ensures softmax writes visible (jt=0)
            for (int idx = tid; idx < JT * 8; idx += 512) {
                int r = idx >> 3, eq = idx & 7;
                *(float4*)&kv[r][eq * 4] =
                    *(const float4*)&vbase[(size_t)(j0 + r) * Edim + eq * 4];
            }
            __syncthreads();
#pragma unroll
            for (int sub = 0; sub < 2; ++sub) {
                int jl = (sub << 6) + gid;
                int j = j0 + jl;
                float4 v4 = *(float4*)&kv[jl][eqg * 4];
#pragma unroll
                for (int ii = 0; ii < TI; ++ii) {
                    int i = i0 + ii;
                    if (j0 + (sub << 6) > i) continue;  // block-uniform skip
                    float p = (j <= i) ? ss[ii][j] : 0.f;
                    int t1 = st1m[ii][j];
                    float4 ev = *(float4*)&sevt[t1][eqg * 4];
                    acc[ii].x = fmaf(p * ev.x, v4.x, acc[ii].x);
                    acc[ii].y = fmaf(p * ev.y, v4.y, acc[ii].y);
                    acc[ii].z = fmaf(p * ev.z, v4.z, acc[ii].z);
                    acc[ii].w = fmaf(p * ev.w, v4.w, acc[ii].w);
                }
            }
        }
        // reduce across the wave's 8 groups (lane bits 3,4,5)
#pragma unroll
        for (int ii = 0; ii < TI; ++ii) {
#pragma unroll
            for (int m = 8; m <= 32; m <<= 1) {
                acc[ii].x += __shfl_xor(acc[ii].x, m);
                acc[ii].y += __shfl_xor(acc[ii].y, m);
                acc[ii].z += __shfl_xor(acc[ii].z, m);
                acc[ii].w += __shfl_xor(acc[ii].w, m);
            }
        }
        __syncthreads();
        if (lane < 8) {
#pragma unroll
            for (int ii = 0; ii < TI; ++ii)
                *(float4*)&spartW[wave][ii][lane * 4] = acc[ii];
        }
        __syncthreads();
        {
            int ii = tid >> 5, e = tid & 31;
            float yv = 0.f;
#pragma unroll
            for (int w = 0; w < 8; ++w) yv += spartW[w][ii][e];
            yv *= sinv[ii];
            y[((size_t)(b * Tdim + i0 + ii)) * Cdim + h * Edim + e] = yv;
        }
    }
}

// ---------------------------------------------------------------------------
// Kernel 4: proj GEMM (M=1024, K=256, N=256) -> d_out (B,T,C)
// ---------------------------------------------------------------------------
__global__ __launch_bounds__(256) void proj_gemm_kernel(
    const float* __restrict__ A, const float* __restrict__ Bw,
    float* __restrict__ out)
{
    const int N = Cdim;
    const int K = Cdim;
    __shared__ float As[16][65];
    __shared__ float Bs[16][64];
    int m0 = blockIdx.y * 64;
    int n0 = blockIdx.x * 64;
    int tid = threadIdx.x;
    int tr = tid >> 4, tc = tid & 15;
    float acc[4][4] = {};
    int ar = tid >> 2, akq = (tid & 3) * 4;
    int bkr = tid >> 4, bcq = (tid & 15) * 4;

    for (int k0 = 0; k0 < K; k0 += 16) {
        float4 av = *(const float4*)(A + (size_t)(m0 + ar) * K + k0 + akq);
        float4 bv = *(const float4*)(Bw + (size_t)(k0 + bkr) * N + n0 + bcq);
        As[akq + 0][ar] = av.x;
        As[akq + 1][ar] = av.y;
        As[akq + 2][ar] = av.z;
        As[akq + 3][ar] = av.w;
        *(float4*)&Bs[bkr][bcq] = bv;
        __syncthreads();
#pragma unroll
        for (int kk = 0; kk < 16; ++kk) {
            float a0 = As[kk][tr * 4 + 0];
            float a1 = As[kk][tr * 4 + 1];
            float a2 = As[kk][tr * 4 + 2];
            float a3 = As[kk][tr * 4 + 3];
            float b0 = Bs[kk][tc * 4 + 0];
            float b1 = Bs[kk][tc * 4 + 1];
            float b2 = Bs[kk][tc * 4 + 2];
            float b3 = Bs[kk][tc * 4 + 3];
            acc[0][0] = fmaf(a0, b0, acc[0][0]);
            acc[0][1] = fmaf(a0, b1, acc[0][1]);
            acc[0][2] = fmaf(a0, b2, acc[0][2]);
            acc[0][3] = fmaf(a0, b3, acc[0][3]);
            acc[1][0] = fmaf(a1, b0, acc[1][0]);
            acc[1][1] = fmaf(a1, b1, acc[1][1]);
            acc[1][2] = fmaf(a1, b2, acc[1][2]);
            acc[1][3] = fmaf(a1, b3, acc[1][3]);
            acc[2][0] = fmaf(a2, b0, acc[2][0]);
            acc[2][1] = fmaf(a2, b1, acc[2][1]);
            acc[2][2] = fmaf(a2, b2, acc[2][2]);
            acc[2][3] = fmaf(a2, b3, acc[2][3]);
            acc[3][0] = fmaf(a3, b0, acc[3][0]);
            acc[3][1] = fmaf(a3, b1, acc[3][1]);
            acc[3][2] = fmaf(a3, b2, acc[3][2]);
            acc[3][3] = fmaf(a3, b3, acc[3][3]);
        }
        __syncthreads();
    }
#pragma unroll
    for (int i = 0; i < 4; ++i) {
#pragma unroll
        for (int j = 0; j < 4; ++j) {
            int m = m0 + tr * 4 + i;
            int nn = n0 + tc * 4 + j;
            out[(size_t)m * N + nn] = acc[i][j];
        }
    }
}

// ---------------------------------------------------------------------------
extern "C" void kernel_launch(void* const* d_in, const int* in_sizes, int n_in,
                              void* d_out, int out_size, void* d_ws, size_t ws_size,
                              hipStream_t stream) {
    (void)in_sizes; (void)n_in; (void)out_size; (void)ws_size;
    const float* x = (const float*)d_in[0];
    const int* bias_matrix = (const int*)d_in[1];
    const float* w_attn = (const float*)d_in[2];
    const float* w_proj = (const float*)d_in[3];
    const float* w_edge_k = (const float*)d_in[4];
    const float* w_edge_v = (const float*)d_in[5];
    const float* edge_emb = (const float*)d_in[6];
    const float* attn_bias = (const float*)d_in[7];
    float* out = (float*)d_out;

    const size_t n_qkv = (size_t)Bdim * Hdim * Tdim * Edim;
    float* ws = (float*)d_ws;
    float* qT = ws;
    float* kT = qT + n_qkv;
    float* vT = kT + n_qkv;
    float* y = vT + n_qkv;
    float* ekt = y + (size_t)Bdim * Tdim * Cdim;
    float* evt = ekt + (size_t)NTYPES * Cdim;

    edge_tables_kernel<<<NTYPES, 256, 0, stream>>>(edge_emb, w_edge_k, w_edge_v,
                                                   ekt, evt);
    qkv_gemm_kernel<<<dim3(12, 16), 256, 0, stream>>>(x, w_attn, qT, kT, vT);
    attn_kernel<<<dim3(16, 16), 512, 0, stream>>>(qT, kT, vT, bias_matrix,
                                                  ekt, evt, attn_bias, y);
    proj_gemm_kernel<<<dim3(4, 16), 256, 0, stream>>>(y, w_proj, out);
}

// Round 3
// 135.893 us; speedup vs baseline: 1.9187x; 1.2056x over previous
//
#include <hip/hip_runtime.h>
#include <hip/hip_bf16.h>
#include <math.h>

// Problem constants
#define Bdim 2
#define Tdim 512
#define Cdim 256
#define Hdim 8
#define Edim 32
#define NTYPES 16
#define TI 8       // i-tile size
#define JT 128     // j-tile size

// ---------------------------------------------------------------------------
// Kernel 1: fused edge-tables + qkv GEMM.
// blocks 0..191: qkv GEMM (M=1024,K=256,N=768), 64x64 tile, scatter (B,H,T,E)
// blocks 192..207: ekt/evt = emb[t] @ w_edge_{k,v}   (16 blocks, 1 per type)
// ---------------------------------------------------------------------------
__global__ __launch_bounds__(256) void pre_kernel(
    const float* __restrict__ A, const float* __restrict__ Bw,
    const float* __restrict__ emb, const float* __restrict__ wk,
    const float* __restrict__ wv,
    float* __restrict__ qT, float* __restrict__ kT, float* __restrict__ vT,
    float* __restrict__ ekt, float* __restrict__ evt)
{
    __shared__ float smem[16 * 68 + 16 * 64];
    int tid = threadIdx.x;

    if (blockIdx.x >= 192) {
        // ---- edge tables ----
        int t = blockIdx.x - 192;
        float* se = smem;
        se[tid] = emb[t * Cdim + tid];
        __syncthreads();
        float a = 0.f, b = 0.f;
        for (int k = 0; k < Cdim; ++k) {
            float ev = se[k];
            a = fmaf(ev, wk[k * Cdim + tid], a);
            b = fmaf(ev, wv[k * Cdim + tid], b);
        }
        ekt[t * Cdim + tid] = a;
        evt[t * Cdim + tid] = b;
        return;
    }

    // ---- qkv GEMM ----
    const int N = 3 * Cdim;
    const int K = Cdim;
    float (*As)[68] = (float(*)[68])smem;            // k-major, aligned rows
    float (*Bs)[64] = (float(*)[64])(smem + 16 * 68);
    int m0 = (blockIdx.x / 12) * 64;
    int n0 = (blockIdx.x % 12) * 64;
    int tr = tid >> 4, tc = tid & 15;
    float acc[4][4] = {};
    int ar = tid >> 2, akq = (tid & 3) * 4;
    int bkr = tid >> 4, bcq = (tid & 15) * 4;

    for (int k0 = 0; k0 < K; k0 += 16) {
        float4 av = *(const float4*)(A + (size_t)(m0 + ar) * K + k0 + akq);
        float4 bv = *(const float4*)(Bw + (size_t)(k0 + bkr) * N + n0 + bcq);
        As[akq + 0][ar] = av.x;
        As[akq + 1][ar] = av.y;
        As[akq + 2][ar] = av.z;
        As[akq + 3][ar] = av.w;
        *(float4*)&Bs[bkr][bcq] = bv;
        __syncthreads();
#pragma unroll
        for (int kk = 0; kk < 16; ++kk) {
            float a0 = As[kk][tr * 4 + 0];
            float a1 = As[kk][tr * 4 + 1];
            float a2 = As[kk][tr * 4 + 2];
            float a3 = As[kk][tr * 4 + 3];
            float b0 = Bs[kk][tc * 4 + 0];
            float b1 = Bs[kk][tc * 4 + 1];
            float b2 = Bs[kk][tc * 4 + 2];
            float b3 = Bs[kk][tc * 4 + 3];
            acc[0][0] = fmaf(a0, b0, acc[0][0]);
            acc[0][1] = fmaf(a0, b1, acc[0][1]);
            acc[0][2] = fmaf(a0, b2, acc[0][2]);
            acc[0][3] = fmaf(a0, b3, acc[0][3]);
            acc[1][0] = fmaf(a1, b0, acc[1][0]);
            acc[1][1] = fmaf(a1, b1, acc[1][1]);
            acc[1][2] = fmaf(a1, b2, acc[1][2]);
            acc[1][3] = fmaf(a1, b3, acc[1][3]);
            acc[2][0] = fmaf(a2, b0, acc[2][0]);
            acc[2][1] = fmaf(a2, b1, acc[2][1]);
            acc[2][2] = fmaf(a2, b2, acc[2][2]);
            acc[2][3] = fmaf(a2, b3, acc[2][3]);
            acc[3][0] = fmaf(a3, b0, acc[3][0]);
            acc[3][1] = fmaf(a3, b1, acc[3][1]);
            acc[3][2] = fmaf(a3, b2, acc[3][2]);
            acc[3][3] = fmaf(a3, b3, acc[3][3]);
        }
        __syncthreads();
    }
#pragma unroll
    for (int i = 0; i < 4; ++i) {
#pragma unroll
        for (int j = 0; j < 4; ++j) {
            int m = m0 + tr * 4 + i;
            int n = n0 + tc * 4 + j;
            int b = m >> 9;
            int t = m & (Tdim - 1);
            int sec = n >> 8;
            int cc = n & (Cdim - 1);
            int h = cc >> 5;
            int e = cc & (Edim - 1);
            float* dst = (sec == 0) ? qT : (sec == 1) ? kT : vT;
            dst[(((size_t)b * Hdim + h) * Tdim + t) * Edim + e] = acc[i][j];
        }
    }
}

// ---------------------------------------------------------------------------
// Kernel 2: attention. grid = (32 tile-pairs, 16 bh), block = 512 (8 waves).
// TI=8 -> LDS ~74 KB -> 2 blocks/CU (16 waves) for barrier overlap.
// Pass A: lane-owns-j scores, qm = q*ekt premultiplied, k-frags in regs.
// Pass B: 8-lane e-quad groups, v in regs, shfl_xor + LDS cross-wave reduce.
// st1i[j][i] int with stride-17 rows: all patterns <=2-way (free).
// ---------------------------------------------------------------------------
__global__ __launch_bounds__(512, 4) void attn_kernel(
    const float* __restrict__ qT, const float* __restrict__ kT,
    const float* __restrict__ vT, const int* __restrict__ bm,
    const float* __restrict__ ekt, const float* __restrict__ evt,
    const float* __restrict__ abt, float* __restrict__ y)
{
    __shared__ float kv[JT][36];                 // k or v tile
    __shared__ float qm[TI][NTYPES][36];         // q*ekt
    __shared__ float ss[TI][516];                // scores -> probs
    __shared__ int   st1i[JT][17];               // bm[b, j, i0+ii] per tile
    __shared__ float sekt[NTYPES][36];
    __shared__ float sevt[NTYPES][36];
    __shared__ float sq[TI][36];
    __shared__ float sabt[NTYPES];
    __shared__ float sinv[TI];
    __shared__ float spartW[8][TI][Edim];

    const int pairIdx = blockIdx.x;   // 0..31
    const int bh = blockIdx.y;        // 0..15
    const int h = bh & (Hdim - 1);
    const int b = bh >> 3;
    const int tid = threadIdx.x;
    const int wave = tid >> 6;
    const int lane = tid & 63;
    const float inv_scale = 0.17677669529663687f;  // 1/sqrt(32)

    const float* qbase = qT + (size_t)bh * Tdim * Edim;
    const float* kbase = kT + (size_t)bh * Tdim * Edim;
    const float* vbase = vT + (size_t)bh * Tdim * Edim;
    const int* bmb = bm + (size_t)b * Tdim * Tdim;

    if (tid < 128) {
        int t = tid >> 3, eq = tid & 7;
        *(float4*)&sekt[t][eq * 4] = *(const float4*)&ekt[t * Cdim + h * Edim + eq * 4];
        *(float4*)&sevt[t][eq * 4] = *(const float4*)&evt[t * Cdim + h * Edim + eq * 4];
    }
    if (tid < NTYPES) sabt[tid] = abt[tid * Hdim + h];

    for (int rep = 0; rep < 2; ++rep) {
        int tau = rep ? (63 - pairIdx) : pairIdx;
        int i0 = tau * TI;
        int imax = i0 + TI - 1;
        int njt = (imax >> 7) + 1;

        __syncthreads();  // tables ready / previous rep fully consumed

        if (tid < TI * 8) {
            int r = tid >> 3, eq = tid & 7;
            *(float4*)&sq[r][eq * 4] =
                *(const float4*)&qbase[(size_t)(i0 + r) * Edim + eq * 4];
        }
        __syncthreads();
        for (int idx = tid; idx < TI * NTYPES * 8; idx += 512) {
            int eq = idx & 7;
            int t = (idx >> 3) & (NTYPES - 1);
            int r = idx >> 7;
            float4 qv = *(float4*)&sq[r][eq * 4];
            float4 ev = *(float4*)&sekt[t][eq * 4];
            float4 o;
            o.x = qv.x * ev.x; o.y = qv.y * ev.y;
            o.z = qv.z * ev.z; o.w = qv.w * ev.w;
            *(float4*)&qm[r][t][eq * 4] = o;
        }

        // ---------------- Pass A: scores ----------------
        for (int jt = 0; jt < njt; ++jt) {
            int j0 = jt << 7;
            __syncthreads();   // prev-tile consumers done (covers qm build on jt=0)
            for (int idx = tid; idx < JT * 8; idx += 512) {
                int r = idx >> 3, eq = idx & 7;
                *(float4*)&kv[r][eq * 4] =
                    *(const float4*)&kbase[(size_t)(j0 + r) * Edim + eq * 4];
            }
            if (tid < 256) {
                int r = tid >> 1, iq = (tid & 1) * 4;
                int4 bmv = *(const int4*)&bmb[(size_t)(j0 + r) * Tdim + i0 + iq];
                st1i[r][iq + 0] = bmv.x;
                st1i[r][iq + 1] = bmv.y;
                st1i[r][iq + 2] = bmv.z;
                st1i[r][iq + 3] = bmv.w;
            }
            __syncthreads();

            int jsub = wave & 1;
            int jl = (jsub << 6) + lane;
            int j = j0 + jl;
            float4 k4[8];
#pragma unroll
            for (int eq = 0; eq < 8; ++eq) k4[eq] = *(float4*)&kv[jl][eq * 4];

#pragma unroll
            for (int u = 0; u < 2; ++u) {
                int ii = (wave >> 1) + u * 4;
                int i = i0 + ii;
                if (j0 + (jsub << 6) > i) continue;   // wave-uniform skip
                int t1 = st1i[jl][ii];
                int t2 = bmb[(size_t)i * Tdim + j];   // L2-resident
                float s = 0.f;
#pragma unroll
                for (int eq = 0; eq < 8; ++eq) {
                    float4 qv = *(float4*)&qm[ii][t1][eq * 4];
                    s = fmaf(qv.x, k4[eq].x, s);
                    s = fmaf(qv.y, k4[eq].y, s);
                    s = fmaf(qv.z, k4[eq].z, s);
                    s = fmaf(qv.w, k4[eq].w, s);
                }
                if (j <= i) ss[ii][j] = s * inv_scale + sabt[t2];
            }
        }
        __syncthreads();

        // ---------------- softmax (normalization deferred) ----------------
        {
            int ii = wave;
            int i = i0 + ii;
            float m = -1e30f;
            for (int j = lane; j <= i; j += 64) m = fmaxf(m, ss[ii][j]);
            for (int off = 32; off; off >>= 1) m = fmaxf(m, __shfl_xor(m, off));
            float sum = 0.f;
            for (int j = lane; j <= i; j += 64) {
                float p = __expf(ss[ii][j] - m);
                ss[ii][j] = p;
                sum += p;
            }
            for (int off = 32; off; off >>= 1) sum += __shfl_xor(sum, off);
            if (lane == 0) sinv[ii] = 1.0f / sum;
        }

        // ---------------- Pass B: PV ----------------
        float4 acc[TI];
#pragma unroll
        for (int ii = 0; ii < TI; ++ii) acc[ii] = make_float4(0.f, 0.f, 0.f, 0.f);
        int gid = tid >> 3;        // 64 groups of 8
        int eqg = tid & 7;
        for (int jt = 0; jt < njt; ++jt) {
            int j0 = jt << 7;
            __syncthreads();   // softmax visible (jt=0) / prev-tile consumers done
            for (int idx = tid; idx < JT * 8; idx += 512) {
                int r = idx >> 3, eq = idx & 7;
                *(float4*)&kv[r][eq * 4] =
                    *(const float4*)&vbase[(size_t)(j0 + r) * Edim + eq * 4];
            }
            if (tid < 256) {
                int r = tid >> 1, iq = (tid & 1) * 4;
                int4 bmv = *(const int4*)&bmb[(size_t)(j0 + r) * Tdim + i0 + iq];
                st1i[r][iq + 0] = bmv.x;
                st1i[r][iq + 1] = bmv.y;
                st1i[r][iq + 2] = bmv.z;
                st1i[r][iq + 3] = bmv.w;
            }
            __syncthreads();
#pragma unroll
            for (int sub = 0; sub < 2; ++sub) {
                int jl = (sub << 6) + gid;
                int j = j0 + jl;
                float4 v4 = *(float4*)&kv[jl][eqg * 4];
#pragma unroll
                for (int ii = 0; ii < TI; ++ii) {
                    int i = i0 + ii;
                    if (j0 + (sub << 6) > i) continue;  // block-uniform skip
                    float p = (j <= i) ? ss[ii][j] : 0.f;
                    int t1 = st1i[jl][ii];
                    float4 ev = *(float4*)&sevt[t1][eqg * 4];
                    acc[ii].x = fmaf(p * ev.x, v4.x, acc[ii].x);
                    acc[ii].y = fmaf(p * ev.y, v4.y, acc[ii].y);
                    acc[ii].z = fmaf(p * ev.z, v4.z, acc[ii].z);
                    acc[ii].w = fmaf(p * ev.w, v4.w, acc[ii].w);
                }
            }
        }
#pragma unroll
        for (int ii = 0; ii < TI; ++ii) {
#pragma unroll
            for (int m = 8; m <= 32; m <<= 1) {
                acc[ii].x += __shfl_xor(acc[ii].x, m);
                acc[ii].y += __shfl_xor(acc[ii].y, m);
                acc[ii].z += __shfl_xor(acc[ii].z, m);
                acc[ii].w += __shfl_xor(acc[ii].w, m);
            }
        }
        __syncthreads();
        if (lane < 8) {
#pragma unroll
            for (int ii = 0; ii < TI; ++ii)
                *(float4*)&spartW[wave][ii][lane * 4] = acc[ii];
        }
        __syncthreads();
        if (tid < TI * Edim) {
            int ii = tid >> 5, e = tid & 31;
            float yv = 0.f;
#pragma unroll
            for (int w = 0; w < 8; ++w) yv += spartW[w][ii][e];
            yv *= sinv[ii];
            y[((size_t)(b * Tdim + i0 + ii)) * Cdim + h * Edim + e] = yv;
        }
    }
}

// ---------------------------------------------------------------------------
// Kernel 3: proj GEMM (M=1024, K=256, N=256) -> d_out (B,T,C)
// ---------------------------------------------------------------------------
__global__ __launch_bounds__(256) void proj_gemm_kernel(
    const float* __restrict__ A, const float* __restrict__ Bw,
    float* __restrict__ out)
{
    const int N = Cdim;
    const int K = Cdim;
    __shared__ float As[16][68];
    __shared__ float Bs[16][64];
    int m0 = blockIdx.y * 64;
    int n0 = blockIdx.x * 64;
    int tid = threadIdx.x;
    int tr = tid >> 4, tc = tid & 15;
    float acc[4][4] = {};
    int ar = tid >> 2, akq = (tid & 3) * 4;
    int bkr = tid >> 4, bcq = (tid & 15) * 4;

    for (int k0 = 0; k0 < K; k0 += 16) {
        float4 av = *(const float4*)(A + (size_t)(m0 + ar) * K + k0 + akq);
        float4 bv = *(const float4*)(Bw + (size_t)(k0 + bkr) * N + n0 + bcq);
        As[akq + 0][ar] = av.x;
        As[akq + 1][ar] = av.y;
        As[akq + 2][ar] = av.z;
        As[akq + 3][ar] = av.w;
        *(float4*)&Bs[bkr][bcq] = bv;
        __syncthreads();
#pragma unroll
        for (int kk = 0; kk < 16; ++kk) {
            float a0 = As[kk][tr * 4 + 0];
            float a1 = As[kk][tr * 4 + 1];
            float a2 = As[kk][tr * 4 + 2];
            float a3 = As[kk][tr * 4 + 3];
            float b0 = Bs[kk][tc * 4 + 0];
            float b1 = Bs[kk][tc * 4 + 1];
            float b2 = Bs[kk][tc * 4 + 2];
            float b3 = Bs[kk][tc * 4 + 3];
            acc[0][0] = fmaf(a0, b0, acc[0][0]);
            acc[0][1] = fmaf(a0, b1, acc[0][1]);
            acc[0][2] = fmaf(a0, b2, acc[0][2]);
            acc[0][3] = fmaf(a0, b3, acc[0][3]);
            acc[1][0] = fmaf(a1, b0, acc[1][0]);
            acc[1][1] = fmaf(a1, b1, acc[1][1]);
            acc[1][2] = fmaf(a1, b2, acc[1][2]);
            acc[1][3] = fmaf(a1, b3, acc[1][3]);
            acc[2][0] = fmaf(a2, b0, acc[2][0]);
            acc[2][1] = fmaf(a2, b1, acc[2][1]);
            acc[2][2] = fmaf(a2, b2, acc[2][2]);
            acc[2][3] = fmaf(a2, b3, acc[2][3]);
            acc[3][0] = fmaf(a3, b0, acc[3][0]);
            acc[3][1] = fmaf(a3, b1, acc[3][1]);
            acc[3][2] = fmaf(a3, b2, acc[3][2]);
            acc[3][3] = fmaf(a3, b3, acc[3][3]);
        }
        __syncthreads();
    }
#pragma unroll
    for (int i = 0; i < 4; ++i) {
#pragma unroll
        for (int j = 0; j < 4; ++j) {
            int m = m0 + tr * 4 + i;
            int nn = n0 + tc * 4 + j;
            out[(size_t)m * N + nn] = acc[i][j];
        }
    }
}

// ---------------------------------------------------------------------------
extern "C" void kernel_launch(void* const* d_in, const int* in_sizes, int n_in,
                              void* d_out, int out_size, void* d_ws, size_t ws_size,
                              hipStream_t stream) {
    (void)in_sizes; (void)n_in; (void)out_size; (void)ws_size;
    const float* x = (const float*)d_in[0];
    const int* bias_matrix = (const int*)d_in[1];
    const float* w_attn = (const float*)d_in[2];
    const float* w_proj = (const float*)d_in[3];
    const float* w_edge_k = (const float*)d_in[4];
    const float* w_edge_v = (const float*)d_in[5];
    const float* edge_emb = (const float*)d_in[6];
    const float* attn_bias = (const float*)d_in[7];
    float* out = (float*)d_out;

    const size_t n_qkv = (size_t)Bdim * Hdim * Tdim * Edim;
    float* ws = (float*)d_ws;
    float* qT = ws;
    float* kT = qT + n_qkv;
    float* vT = kT + n_qkv;
    float* y = vT + n_qkv;
    float* ekt = y + (size_t)Bdim * Tdim * Cdim;
    float* evt = ekt + (size_t)NTYPES * Cdim;

    pre_kernel<<<208, 256, 0, stream>>>(x, w_attn, edge_emb, w_edge_k, w_edge_v,
                                        qT, kT, vT, ekt, evt);
    attn_kernel<<<dim3(32, 16), 512, 0, stream>>>(qT, kT, vT, bias_matrix,
                                                  ekt, evt, attn_bias, y);
    proj_gemm_kernel<<<dim3(4, 16), 256, 0, stream>>>(y, w_proj, out);
}